// Round 23
// baseline (166.793 us; speedup 1.0000x reference)
//
#include <hip/hip_runtime.h>
#include <math.h>

#define BB   4
#define CC   64
#define KK   64
#define DDim 16
#define HDim 64
#define WDim 64
#define SS   (DDim*HDim*WDim)   /* 65536 */
#define PLANE (HDim*WDim)       /* 4096  */
#define NCH2 64                 /* gemm1 s-chunks per batch (chunk = 1024) */
#define TOPN 6
#define RSTR 68                 /* ring row stride */
#define RROWS 18                /* 16 output rows + 2 halo rows per slot */
#define NSTG 288                /* RROWS*16 float4 per plane slot */

typedef __attribute__((ext_vector_type(8))) short bf16x8;
typedef __attribute__((ext_vector_type(4))) float f32x4;

__device__ __forceinline__ unsigned cvt_pk_bf16(float lo, float hi) {
    unsigned r;
    asm("v_cvt_pk_bf16_f32 %0, %1, %2" : "=v"(r) : "v"(lo), "v"(hi));
    return r;
}
__device__ __forceinline__ float bf2f(unsigned short u) {
    union { unsigned u; float f; } v; v.u = ((unsigned)u) << 16; return v.f;
}

// ---------------------------------------------------------------------------
// Kernel 1: depthwise 3x3x3 conv (SAME), UNIFORM blocks (round-19 champion,
// 85us): every block computes q AND k AND v for one (b, c, h-quarter).
// Two 4-slot LDS rings (xq + xkv), each [18][68] f32 -> 38.3 KB -> 4
// blocks/CU at 128 threads. grid = 1024. One barrier per step:
// SLOAD2(d+2) early -> COMPUTE(d) -> SWRITE2(d+2) slot (d+2)&3 -> barrier.
// Bank-uniform pad-68 linear writes + b128 reads; w-halos via __shfl;
// OOB rows/planes staged ZEROS. Outputs packed bf16.
// ---------------------------------------------------------------------------
__global__ __launch_bounds__(128) void conv_uni(
    const float* __restrict__ xq, const float* __restrict__ xkv,
    const float* __restrict__ wq, const float* __restrict__ bq,
    const float* __restrict__ wk, const float* __restrict__ bk,
    const float* __restrict__ wv, const float* __restrict__ bv,
    unsigned short* __restrict__ qo, unsigned short* __restrict__ ko,
    unsigned short* __restrict__ vo)
{
    __shared__ float ringQ[4][RROWS*RSTR];     // 19.2 KB
    __shared__ float ringK[4][RROWS*RSTR];     // 19.2 KB

    // bijective XCD swizzle: 1024 blocks / 8 XCDs = 128 contiguous per XCD
    int bid  = blockIdx.x;
    int work = (bid & 7) * 128 + (bid >> 3);
    int b  = work >> 8;
    int c  = (work >> 2) & 63;
    int hq = work & 3;
    int g0 = hq << 4;

    const float* srcQ = xq  + (size_t)(b*CC + c) * SS;
    const float* srcK = xkv + (size_t)(b*CC + c) * SS;
    float wQ[27], wK[27], wV[27];
    #pragma unroll
    for (int i = 0; i < 27; ++i) {
        wQ[i] = wq[c*27 + i];
        wK[i] = wk[c*27 + i];
        wV[i] = wv[c*27 + i];
    }
    const float bQ = bq[c], bK = bk[c], bV = bv[c];

    unsigned short* dQ = qo + (size_t)(b*CC + c) * SS;
    unsigned short* dK = ko + (size_t)(b*CC + c) * SS;
    unsigned short* dV = vo + (size_t)(b*CC + c) * SS;

    const int tid  = threadIdx.x;
    const int lane = tid & 63;
    const int wg   = tid & 7;                  // w-group; wg+-1 same wave
    const int w0   = wg << 3;
    const int hl   = tid >> 3;                 // 0..15 local output row
    const int y    = g0 + hl;

    // staging: 18 rows x 16 chunks = 288 float4 per input; 3 masked iters
    float4 stgQ[3], stgK[3];
#define SLOAD2(p) {                                                            \
    const int p_ = (p);                                                        \
    const bool pv_ = (p_ >= 0 && p_ < DDim);                                   \
    _Pragma("unroll")                                                          \
    for (int i_ = 0; i_ < 3; ++i_) {                                           \
        const int fidx_ = i_*128 + tid;                                        \
        const int row_  = fidx_ >> 4;                                          \
        const int gy_   = g0 - 1 + row_;                                       \
        float4 vq_ = make_float4(0.f,0.f,0.f,0.f), vk_ = vq_;                  \
        if (pv_ && fidx_ < NSTG && gy_ >= 0 && gy_ < HDim) {                   \
            const size_t o_ = (size_t)p_*PLANE + gy_*WDim + (fidx_ & 15)*4;    \
            vq_ = *(const float4*)(srcQ + o_);                                 \
            vk_ = *(const float4*)(srcK + o_);                                 \
        }                                                                      \
        stgQ[i_] = vq_; stgK[i_] = vk_;                                        \
    } }
#define SWRITE2(p) {                                                           \
    float* RQ_ = ringQ[(p) & 3];                                               \
    float* RK_ = ringK[(p) & 3];                                               \
    _Pragma("unroll")                                                          \
    for (int i_ = 0; i_ < 3; ++i_) {                                           \
        const int fidx_ = i_*128 + tid;                                        \
        if (fidx_ < NSTG) {                                                    \
            const int off_ = (fidx_ >> 4)*RSTR + (fidx_ & 15)*4;               \
            *(float4*)&RQ_[off_] = stgQ[i_];                                   \
            *(float4*)&RK_[off_] = stgK[i_];                                   \
        }                                                                      \
    } }

// branch-free plane compute: q from ringQ, k+v from shared ringK window
#define COMPUTE_D(dd) {                                                        \
    float accQ[8], accK[8], accV[8];                                           \
    _Pragma("unroll")                                                          \
    for (int j = 0; j < 8; ++j) { accQ[j] = bQ; accK[j] = bK; accV[j] = bV; }  \
    _Pragma("unroll")                                                          \
    for (int dz = 0; dz < 3; ++dz) {                                           \
        const float* RQ = ringQ[((dd) + dz + 3) & 3];      /* plane dd+dz-1 */ \
        const float* RK = ringK[((dd) + dz + 3) & 3];                          \
        _Pragma("unroll")                                                      \
        for (int dy = 0; dy < 3; ++dy) {                                       \
            const int base_ = (hl + dy)*RSTR;                                  \
            float4 qa0 = *(const float4*)&RQ[base_ + w0];                      \
            float4 qa1 = *(const float4*)&RQ[base_ + w0 + 4];                  \
            float4 ka0 = *(const float4*)&RK[base_ + w0];                      \
            float4 ka1 = *(const float4*)&RK[base_ + w0 + 4];                  \
            float qlh = __shfl(qa1.w, lane - 1, 64);                           \
            float qrh = __shfl(qa0.x, lane + 1, 64);                           \
            float klh = __shfl(ka1.w, lane - 1, 64);                           \
            float krh = __shfl(ka0.x, lane + 1, 64);                           \
            float rq[10], rk[10];                                              \
            rq[0] = wg       ? qlh : 0.f;                                      \
            rq[9] = (wg < 7) ? qrh : 0.f;                                      \
            rq[1]=qa0.x; rq[2]=qa0.y; rq[3]=qa0.z; rq[4]=qa0.w;                \
            rq[5]=qa1.x; rq[6]=qa1.y; rq[7]=qa1.z; rq[8]=qa1.w;                \
            rk[0] = wg       ? klh : 0.f;                                      \
            rk[9] = (wg < 7) ? krh : 0.f;                                      \
            rk[1]=ka0.x; rk[2]=ka0.y; rk[3]=ka0.z; rk[4]=ka0.w;                \
            rk[5]=ka1.x; rk[6]=ka1.y; rk[7]=ka1.z; rk[8]=ka1.w;                \
            const float cq0 = wQ[dz*9 + dy*3 + 0];                             \
            const float cq1 = wQ[dz*9 + dy*3 + 1];                             \
            const float cq2 = wQ[dz*9 + dy*3 + 2];                             \
            const float ck0 = wK[dz*9 + dy*3 + 0];                             \
            const float ck1 = wK[dz*9 + dy*3 + 1];                             \
            const float ck2 = wK[dz*9 + dy*3 + 2];                             \
            const float cv0 = wV[dz*9 + dy*3 + 0];                             \
            const float cv1 = wV[dz*9 + dy*3 + 1];                             \
            const float cv2 = wV[dz*9 + dy*3 + 2];                             \
            _Pragma("unroll")                                                  \
            for (int j = 0; j < 8; ++j) {                                      \
                float sQ = fmaf(cq0, rq[j],   accQ[j]);                        \
                sQ       = fmaf(cq1, rq[j+1], sQ);                             \
                accQ[j]  = fmaf(cq2, rq[j+2], sQ);                             \
                float sK = fmaf(ck0, rk[j],   accK[j]);                        \
                sK       = fmaf(ck1, rk[j+1], sK);                             \
                accK[j]  = fmaf(ck2, rk[j+2], sK);                             \
                float sV = fmaf(cv0, rk[j],   accV[j]);                        \
                sV       = fmaf(cv1, rk[j+1], sV);                             \
                accV[j]  = fmaf(cv2, rk[j+2], sV);                             \
            }                                                                  \
        }                                                                      \
    }                                                                          \
    const int off = (dd)*PLANE + y*WDim + w0;                                  \
    uint4 pq, pk, pv;                                                          \
    pq.x = cvt_pk_bf16(accQ[0], accQ[1]);                                      \
    pq.y = cvt_pk_bf16(accQ[2], accQ[3]);                                      \
    pq.z = cvt_pk_bf16(accQ[4], accQ[5]);                                      \
    pq.w = cvt_pk_bf16(accQ[6], accQ[7]);                                      \
    pk.x = cvt_pk_bf16(accK[0], accK[1]);                                      \
    pk.y = cvt_pk_bf16(accK[2], accK[3]);                                      \
    pk.z = cvt_pk_bf16(accK[4], accK[5]);                                      \
    pk.w = cvt_pk_bf16(accK[6], accK[7]);                                      \
    pv.x = cvt_pk_bf16(accV[0], accV[1]);                                      \
    pv.y = cvt_pk_bf16(accV[2], accV[3]);                                      \
    pv.z = cvt_pk_bf16(accV[4], accV[5]);                                      \
    pv.w = cvt_pk_bf16(accV[6], accV[7]);                                      \
    *(uint4*)&dQ[off] = pq;                                                    \
    *(uint4*)&dK[off] = pk;                                                    \
    *(uint4*)&dV[off] = pv;                                                    \
    }

    // prologue: slots <- planes -1 (zeros), 0, 1
    SLOAD2(-1); SWRITE2(-1);
    SLOAD2(0);  SWRITE2(0);
    SLOAD2(1);  SWRITE2(1);
    __syncthreads();

    for (int d = 0; d < DDim; ++d) {
        if (d < DDim - 1) SLOAD2(d + 2);       // issue early (zeros if p>=16)
        COMPUTE_D(d);
        if (d < DDim - 1) SWRITE2(d + 2);      // slot (d+2)&3 disjoint
        __syncthreads();
    }
#undef SLOAD2
#undef SWRITE2
#undef COMPUTE_D
}

// ---------------------------------------------------------------------------
// Kernel 2: gemm1 via bf16 MFMA 16x16x32 (round-19 LDS-staged version).
// Block = (b, chunk of 1024 s); grid = 4*64 = 256 x 256 thr (4 waves).
// Per 128-s subtile: stage q,k bf16 [64][136] (pad 8), barrier, 4 K-steps.
// Wave w owns c-rows [16w,16w+16); partial attn[64][64] per block.
// ---------------------------------------------------------------------------
__global__ __launch_bounds__(256) void gemm1_mfma(
    const unsigned short* __restrict__ qb, const unsigned short* __restrict__ kb,
    float* __restrict__ part)
{
    __shared__ unsigned short lq[64*136];
    __shared__ unsigned short lk[64*136];

    int bid   = blockIdx.x;
    int b     = bid >> 6;
    int chunk = bid & 63;
    int tid   = threadIdx.x;
    int lane  = tid & 63;
    int wid   = tid >> 6;
    int c0    = wid << 4;
    int lr    = lane & 15;
    int kq    = lane >> 4;

    const unsigned short* qsrc = qb + (size_t)b*CC*SS;
    const unsigned short* ksrc = kb + (size_t)b*KK*SS;

    f32x4 acc[4];
    #pragma unroll
    for (int j = 0; j < 4; ++j) acc[j] = (f32x4){0.f, 0.f, 0.f, 0.f};

    const int sbase = chunk << 10;                     // 1024 s per block
    for (int sc = 0; sc < 8; ++sc) {
        const int s0 = sbase + (sc << 7);              // 128-s subtile
        __syncthreads();
        #pragma unroll
        for (int it = 0; it < 8; ++it) {
            const int idx  = it*256 + tid;             // 0..2047
            const int tile = idx >> 10;
            const int row  = (idx >> 4) & 63;
            const int ch8  = idx & 15;
            const unsigned short* s_ = (tile ? ksrc : qsrc) + (size_t)row*SS + s0 + ch8*8;
            unsigned short* d_ = (tile ? lk : lq) + row*136 + ch8*8;
            *(uint4*)d_ = *(const uint4*)s_;
        }
        __syncthreads();
        #pragma unroll
        for (int ss = 0; ss < 4; ++ss) {
            const int scol = ss*32 + kq*8;
            bf16x8 a = *(const bf16x8*)&lq[(c0 + lr)*136 + scol];
            #pragma unroll
            for (int j = 0; j < 4; ++j) {
                bf16x8 bv = *(const bf16x8*)&lk[(j*16 + lr)*136 + scol];
                acc[j] = __builtin_amdgcn_mfma_f32_16x16x32_bf16(a, bv, acc[j], 0, 0, 0);
            }
        }
    }

    float* pb = part + ((size_t)(b*NCH2 + chunk)) * (CC*KK);
    #pragma unroll
    for (int j = 0; j < 4; ++j)
        #pragma unroll
        for (int r = 0; r < 4; ++r)
            pb[(c0 + kq*4 + r)*KK + j*16 + lr] = acc[j][r];
}

// ---------------------------------------------------------------------------
// Kernel 3: reduce 64 chunk-partials -> attn logits (x 1/sqrt(64) = 0.125)
// ---------------------------------------------------------------------------
__global__ __launch_bounds__(256) void reduce_attn(
    const float* __restrict__ part, float* __restrict__ attn)
{
    int bid = blockIdx.x;            // b*64 + c
    int b = bid >> 6, c = bid & 63;
    int tid = threadIdx.x;
    int k = tid & 63, g = tid >> 6;
    float s = 0.f;
    for (int ch = g; ch < NCH2; ch += 4)
        s += part[(size_t)(b*NCH2 + ch)*(CC*KK) + c*KK + k];
    __shared__ float red[256];
    red[tid] = s;
    __syncthreads();
    if (tid < 64) {
        float tot = red[tid] + red[tid+64] + red[tid+128] + red[tid+192];
        attn[b*CC*KK + c*KK + tid] = tot * 0.125f;
    }
}

// ---------------------------------------------------------------------------
// Kernel 4: per-batch softmax over K (rows) + top-6 mask per column over C.
// Strict ">" == lax.top_k lowest-index-first tie break. Writes attn_m (out 1).
// ---------------------------------------------------------------------------
__global__ __launch_bounds__(64) void softmax_topk(
    const float* __restrict__ attn, float* __restrict__ attn_m)
{
    __shared__ float p[64*65];
    int b = blockIdx.x;
    int t = threadIdx.x;
    for (int i = 0; i < 64; ++i) p[i*65 + t] = attn[b*4096 + i*64 + t];
    __syncthreads();
    float m = -1e30f;
    for (int k = 0; k < 64; ++k) m = fmaxf(m, p[t*65 + k]);
    float sum = 0.f;
    for (int k = 0; k < 64; ++k) { float e = expf(p[t*65+k] - m); p[t*65+k] = e; sum += e; }
    float inv = 1.f / sum;
    for (int k = 0; k < 64; ++k) p[t*65+k] *= inv;
    __syncthreads();
    unsigned long long chosen = 0ull;
    #pragma unroll
    for (int pass = 0; pass < TOPN; ++pass) {
        float best = -1.f; int bi = 0;
        for (int c2 = 0; c2 < 64; ++c2) {
            float v = p[c2*65 + t];
            if (!((chosen >> c2) & 1ull) && v > best) { best = v; bi = c2; }
        }
        chosen |= 1ull << bi;
    }
    for (int c2 = 0; c2 < 64; ++c2) {
        float v = p[c2*65 + t];
        attn_m[b*4096 + c2*64 + t] = ((chosen >> c2) & 1ull) ? v : 0.f;
    }
}

// ---------------------------------------------------------------------------
// Kernel 5: out = x_q + attn_m @ v  -- SPARSE: attn_m has exactly <=384
// nonzeros of 4096 per batch (top-6-per-column mask). Build a per-block CSR
// (k-ascending per row -> summation order identical to the dense loop,
// bit-exact since adding 0.0f is the identity) and iterate only nonzeros:
// ~6 avg entries/row vs 64 -> 10x fewer FMA + LDS reads. vt staging and
// residual unchanged. LDS 51 -> ~37 KB (4 blocks/CU).
// ---------------------------------------------------------------------------
__global__ __launch_bounds__(256) void gemm2_sparse(
    const float* __restrict__ attn_m, const unsigned short* __restrict__ v,
    const float* __restrict__ xq, float* __restrict__ out)
{
    __shared__ float vt[64][132];    // [k][s] f32 (unpacked from bf16)
    __shared__ float eV[384];
    __shared__ int   eK[384];
    __shared__ int   rp[65];
    __shared__ int   cnt[64];

    int bid = blockIdx.x;
    int b  = bid >> 7;
    int ch = bid & 127;
    int tid = threadIdx.x;

    // ---- build CSR of attn_m rows (deterministic, k ascending) ----
    const float* am = attn_m + (size_t)b*4096;
    if (tid < 64) {
        int n = 0;
        for (int k = 0; k < 64; ++k) n += (am[tid*64 + k] != 0.f) ? 1 : 0;
        cnt[tid] = n;
    }
    __syncthreads();
    if (tid == 0) {
        int a = 0;
        for (int c = 0; c < 64; ++c) { rp[c] = a; a += cnt[c]; }
        rp[64] = a;
    }
    __syncthreads();
    if (tid < 64) {
        int w = rp[tid];
        for (int k = 0; k < 64; ++k) {
            float val = am[tid*64 + k];
            if (val != 0.f) { eV[w] = val; eK[w] = k; ++w; }
        }
    }
    // visibility guaranteed by the barrier inside the subtile loop below

    int c0 = (tid >> 4) * 4;      // 0..60
    int s0 = (tid & 15) * 8;      // 0..120
    const unsigned short* vb = v + (size_t)b*KK*SS;
    const float* xb = xq + (size_t)b*CC*SS;
    float* ob = out + (size_t)b*CC*SS;
    int sb0 = ch * 512;
    for (int st = 0; st < 4; ++st) {
        int sb = sb0 + st*128;
        __syncthreads();
        #pragma unroll
        for (int i = 0; i < 4; ++i) {
            int idx = i*256 + tid;             // 0..1023
            int k   = idx >> 4;                // 0..63
            int s8  = (idx & 15) * 8;          // 0..120
            uint4 pk = *(const uint4*)&vb[(size_t)k*SS + sb + s8];
            float* dst = &vt[k][s8];
            dst[0] = bf2f((unsigned short)(pk.x & 0xffff));
            dst[1] = bf2f((unsigned short)(pk.x >> 16));
            dst[2] = bf2f((unsigned short)(pk.y & 0xffff));
            dst[3] = bf2f((unsigned short)(pk.y >> 16));
            dst[4] = bf2f((unsigned short)(pk.z & 0xffff));
            dst[5] = bf2f((unsigned short)(pk.z >> 16));
            dst[6] = bf2f((unsigned short)(pk.w & 0xffff));
            dst[7] = bf2f((unsigned short)(pk.w >> 16));
        }
        __syncthreads();
        float acc[4][8] = {};
        #pragma unroll
        for (int r = 0; r < 4; ++r) {
            const int e0 = rp[c0 + r];
            const int e1 = rp[c0 + r + 1];
            for (int i = e0; i < e1; ++i) {    // avg ~6 iterations
                const float val = eV[i];
                const int   k   = eK[i];
                float4 v0 = *(const float4*)&vt[k][s0];
                float4 v1 = *(const float4*)&vt[k][s0+4];
                acc[r][0] = fmaf(val, v0.x, acc[r][0]);
                acc[r][1] = fmaf(val, v0.y, acc[r][1]);
                acc[r][2] = fmaf(val, v0.z, acc[r][2]);
                acc[r][3] = fmaf(val, v0.w, acc[r][3]);
                acc[r][4] = fmaf(val, v1.x, acc[r][4]);
                acc[r][5] = fmaf(val, v1.y, acc[r][5]);
                acc[r][6] = fmaf(val, v1.z, acc[r][6]);
                acc[r][7] = fmaf(val, v1.w, acc[r][7]);
            }
        }
        #pragma unroll
        for (int r = 0; r < 4; ++r) {
            int off = (c0+r)*SS + sb + s0;
            float4 x0 = *(const float4*)&xb[off];
            float4 x1 = *(const float4*)&xb[off+4];
            *(float4*)&ob[off]   = make_float4(acc[r][0]+x0.x, acc[r][1]+x0.y,
                                               acc[r][2]+x0.z, acc[r][3]+x0.w);
            *(float4*)&ob[off+4] = make_float4(acc[r][4]+x1.x, acc[r][5]+x1.y,
                                               acc[r][6]+x1.z, acc[r][7]+x1.w);
        }
    }
}

// ---------------------------------------------------------------------------
extern "C" void kernel_launch(void* const* d_in, const int* in_sizes, int n_in,
                              void* d_out, int out_size, void* d_ws, size_t ws_size,
                              hipStream_t stream)
{
    const float* xq  = (const float*)d_in[0];
    const float* xkv = (const float*)d_in[1];
    const float* wq  = (const float*)d_in[2];
    const float* bq  = (const float*)d_in[3];
    const float* wk  = (const float*)d_in[4];
    const float* bk  = (const float*)d_in[5];
    const float* wv  = (const float*)d_in[6];
    const float* bv  = (const float*)d_in[7];
    float* out = (float*)d_out;

    // workspace: k (bf16 32MB), v (bf16 32MB), part (4MB), attn (64KB)
    unsigned short* k_ws = (unsigned short*)d_ws;
    unsigned short* v_ws = k_ws + (size_t)BB*KK*SS;
    float* part = (float*)(v_ws + (size_t)BB*KK*SS);
    float* attn = part + (size_t)BB*NCH2*CC*KK;

    unsigned short* q_bf = (unsigned short*)out;  // 32MB in out region,
                                                  // overwritten by gemm2
    float* attn_m = out + (size_t)BB*CC*SS;       // output 1 (B*C*K floats)

    conv_uni    <<<BB*CC*4,  128, 0, stream>>>(xq, xkv, wq, bq, wk, bk, wv, bv,
                                               q_bf, k_ws, v_ws);
    gemm1_mfma  <<<BB*NCH2,  256, 0, stream>>>(q_bf, k_ws, part);
    reduce_attn <<<BB*CC,    256, 0, stream>>>(part, attn);
    softmax_topk<<<BB,        64, 0, stream>>>(attn, attn_m);
    gemm2_sparse<<<BB*128,   256, 0, stream>>>(attn_m, v_ws, xq, out);
}

// Round 24
// 139.799 us; speedup vs baseline: 1.1931x; 1.1931x over previous
//
#include <hip/hip_runtime.h>
#include <math.h>

#define BB   4
#define CC   64
#define KK   64
#define DDim 16
#define HDim 64
#define WDim 64
#define SS   (DDim*HDim*WDim)   /* 65536 */
#define PLANE (HDim*WDim)       /* 4096  */
#define NCH2 64                 /* gemm1 s-chunks per batch (chunk = 1024) */
#define TOPN 6
#define RSTR 68                 /* ring row stride */
#define RROWS 18                /* 16 output rows + 2 halo rows per slot */
#define NSTG 288                /* RROWS*16 float4 per plane slot */

typedef __attribute__((ext_vector_type(8))) short bf16x8;
typedef __attribute__((ext_vector_type(4))) float f32x4;

__device__ __forceinline__ unsigned cvt_pk_bf16(float lo, float hi) {
    unsigned r;
    asm("v_cvt_pk_bf16_f32 %0, %1, %2" : "=v"(r) : "v"(lo), "v"(hi));
    return r;
}
__device__ __forceinline__ float bf2f(unsigned short u) {
    union { unsigned u; float f; } v; v.u = ((unsigned)u) << 16; return v.f;
}

// ---------------------------------------------------------------------------
// Kernel 1: depthwise 3x3x3 conv (SAME), UNIFORM blocks (round-19 champion):
// every block computes q AND k AND v for one (b, c, h-quarter).
// Two 4-slot LDS rings (xq + xkv), each [18][68] f32 -> 38.3 KB -> 4
// blocks/CU at 128 threads. grid = 1024. One barrier per step:
// SLOAD2(d+2) early -> COMPUTE(d) -> SWRITE2(d+2) slot (d+2)&3 -> barrier.
// Bank-uniform pad-68 linear writes + b128 reads; w-halos via __shfl;
// OOB rows/planes staged ZEROS. Outputs packed bf16.
// ---------------------------------------------------------------------------
__global__ __launch_bounds__(128) void conv_uni(
    const float* __restrict__ xq, const float* __restrict__ xkv,
    const float* __restrict__ wq, const float* __restrict__ bq,
    const float* __restrict__ wk, const float* __restrict__ bk,
    const float* __restrict__ wv, const float* __restrict__ bv,
    unsigned short* __restrict__ qo, unsigned short* __restrict__ ko,
    unsigned short* __restrict__ vo)
{
    __shared__ float ringQ[4][RROWS*RSTR];     // 19.2 KB
    __shared__ float ringK[4][RROWS*RSTR];     // 19.2 KB

    // bijective XCD swizzle: 1024 blocks / 8 XCDs = 128 contiguous per XCD
    int bid  = blockIdx.x;
    int work = (bid & 7) * 128 + (bid >> 3);
    int b  = work >> 8;
    int c  = (work >> 2) & 63;
    int hq = work & 3;
    int g0 = hq << 4;

    const float* srcQ = xq  + (size_t)(b*CC + c) * SS;
    const float* srcK = xkv + (size_t)(b*CC + c) * SS;
    float wQ[27], wK[27], wV[27];
    #pragma unroll
    for (int i = 0; i < 27; ++i) {
        wQ[i] = wq[c*27 + i];
        wK[i] = wk[c*27 + i];
        wV[i] = wv[c*27 + i];
    }
    const float bQ = bq[c], bK = bk[c], bV = bv[c];

    unsigned short* dQ = qo + (size_t)(b*CC + c) * SS;
    unsigned short* dK = ko + (size_t)(b*CC + c) * SS;
    unsigned short* dV = vo + (size_t)(b*CC + c) * SS;

    const int tid  = threadIdx.x;
    const int lane = tid & 63;
    const int wg   = tid & 7;                  // w-group; wg+-1 same wave
    const int w0   = wg << 3;
    const int hl   = tid >> 3;                 // 0..15 local output row
    const int y    = g0 + hl;

    // staging: 18 rows x 16 chunks = 288 float4 per input; 3 masked iters
    float4 stgQ[3], stgK[3];
#define SLOAD2(p) {                                                            \
    const int p_ = (p);                                                        \
    const bool pv_ = (p_ >= 0 && p_ < DDim);                                   \
    _Pragma("unroll")                                                          \
    for (int i_ = 0; i_ < 3; ++i_) {                                           \
        const int fidx_ = i_*128 + tid;                                        \
        const int row_  = fidx_ >> 4;                                          \
        const int gy_   = g0 - 1 + row_;                                       \
        float4 vq_ = make_float4(0.f,0.f,0.f,0.f), vk_ = vq_;                  \
        if (pv_ && fidx_ < NSTG && gy_ >= 0 && gy_ < HDim) {                   \
            const size_t o_ = (size_t)p_*PLANE + gy_*WDim + (fidx_ & 15)*4;    \
            vq_ = *(const float4*)(srcQ + o_);                                 \
            vk_ = *(const float4*)(srcK + o_);                                 \
        }                                                                      \
        stgQ[i_] = vq_; stgK[i_] = vk_;                                        \
    } }
#define SWRITE2(p) {                                                           \
    float* RQ_ = ringQ[(p) & 3];                                               \
    float* RK_ = ringK[(p) & 3];                                               \
    _Pragma("unroll")                                                          \
    for (int i_ = 0; i_ < 3; ++i_) {                                           \
        const int fidx_ = i_*128 + tid;                                        \
        if (fidx_ < NSTG) {                                                    \
            const int off_ = (fidx_ >> 4)*RSTR + (fidx_ & 15)*4;               \
            *(float4*)&RQ_[off_] = stgQ[i_];                                   \
            *(float4*)&RK_[off_] = stgK[i_];                                   \
        }                                                                      \
    } }

// branch-free plane compute: q from ringQ, k+v from shared ringK window
#define COMPUTE_D(dd) {                                                        \
    float accQ[8], accK[8], accV[8];                                           \
    _Pragma("unroll")                                                          \
    for (int j = 0; j < 8; ++j) { accQ[j] = bQ; accK[j] = bK; accV[j] = bV; }  \
    _Pragma("unroll")                                                          \
    for (int dz = 0; dz < 3; ++dz) {                                           \
        const float* RQ = ringQ[((dd) + dz + 3) & 3];      /* plane dd+dz-1 */ \
        const float* RK = ringK[((dd) + dz + 3) & 3];                          \
        _Pragma("unroll")                                                      \
        for (int dy = 0; dy < 3; ++dy) {                                       \
            const int base_ = (hl + dy)*RSTR;                                  \
            float4 qa0 = *(const float4*)&RQ[base_ + w0];                      \
            float4 qa1 = *(const float4*)&RQ[base_ + w0 + 4];                  \
            float4 ka0 = *(const float4*)&RK[base_ + w0];                      \
            float4 ka1 = *(const float4*)&RK[base_ + w0 + 4];                  \
            float qlh = __shfl(qa1.w, lane - 1, 64);                           \
            float qrh = __shfl(qa0.x, lane + 1, 64);                           \
            float klh = __shfl(ka1.w, lane - 1, 64);                           \
            float krh = __shfl(ka0.x, lane + 1, 64);                           \
            float rq[10], rk[10];                                              \
            rq[0] = wg       ? qlh : 0.f;                                      \
            rq[9] = (wg < 7) ? qrh : 0.f;                                      \
            rq[1]=qa0.x; rq[2]=qa0.y; rq[3]=qa0.z; rq[4]=qa0.w;                \
            rq[5]=qa1.x; rq[6]=qa1.y; rq[7]=qa1.z; rq[8]=qa1.w;                \
            rk[0] = wg       ? klh : 0.f;                                      \
            rk[9] = (wg < 7) ? krh : 0.f;                                      \
            rk[1]=ka0.x; rk[2]=ka0.y; rk[3]=ka0.z; rk[4]=ka0.w;                \
            rk[5]=ka1.x; rk[6]=ka1.y; rk[7]=ka1.z; rk[8]=ka1.w;                \
            const float cq0 = wQ[dz*9 + dy*3 + 0];                             \
            const float cq1 = wQ[dz*9 + dy*3 + 1];                             \
            const float cq2 = wQ[dz*9 + dy*3 + 2];                             \
            const float ck0 = wK[dz*9 + dy*3 + 0];                             \
            const float ck1 = wK[dz*9 + dy*3 + 1];                             \
            const float ck2 = wK[dz*9 + dy*3 + 2];                             \
            const float cv0 = wV[dz*9 + dy*3 + 0];                             \
            const float cv1 = wV[dz*9 + dy*3 + 1];                             \
            const float cv2 = wV[dz*9 + dy*3 + 2];                             \
            _Pragma("unroll")                                                  \
            for (int j = 0; j < 8; ++j) {                                      \
                float sQ = fmaf(cq0, rq[j],   accQ[j]);                        \
                sQ       = fmaf(cq1, rq[j+1], sQ);                             \
                accQ[j]  = fmaf(cq2, rq[j+2], sQ);                             \
                float sK = fmaf(ck0, rk[j],   accK[j]);                        \
                sK       = fmaf(ck1, rk[j+1], sK);                             \
                accK[j]  = fmaf(ck2, rk[j+2], sK);                             \
                float sV = fmaf(cv0, rk[j],   accV[j]);                        \
                sV       = fmaf(cv1, rk[j+1], sV);                             \
                accV[j]  = fmaf(cv2, rk[j+2], sV);                             \
            }                                                                  \
        }                                                                      \
    }                                                                          \
    const int off = (dd)*PLANE + y*WDim + w0;                                  \
    uint4 pq, pk, pv;                                                          \
    pq.x = cvt_pk_bf16(accQ[0], accQ[1]);                                      \
    pq.y = cvt_pk_bf16(accQ[2], accQ[3]);                                      \
    pq.z = cvt_pk_bf16(accQ[4], accQ[5]);                                      \
    pq.w = cvt_pk_bf16(accQ[6], accQ[7]);                                      \
    pk.x = cvt_pk_bf16(accK[0], accK[1]);                                      \
    pk.y = cvt_pk_bf16(accK[2], accK[3]);                                      \
    pk.z = cvt_pk_bf16(accK[4], accK[5]);                                      \
    pk.w = cvt_pk_bf16(accK[6], accK[7]);                                      \
    pv.x = cvt_pk_bf16(accV[0], accV[1]);                                      \
    pv.y = cvt_pk_bf16(accV[2], accV[3]);                                      \
    pv.z = cvt_pk_bf16(accV[4], accV[5]);                                      \
    pv.w = cvt_pk_bf16(accV[6], accV[7]);                                      \
    *(uint4*)&dQ[off] = pq;                                                    \
    *(uint4*)&dK[off] = pk;                                                    \
    *(uint4*)&dV[off] = pv;                                                    \
    }

    // prologue: slots <- planes -1 (zeros), 0, 1
    SLOAD2(-1); SWRITE2(-1);
    SLOAD2(0);  SWRITE2(0);
    SLOAD2(1);  SWRITE2(1);
    __syncthreads();

    for (int d = 0; d < DDim; ++d) {
        if (d < DDim - 1) SLOAD2(d + 2);       // issue early (zeros if p>=16)
        COMPUTE_D(d);
        if (d < DDim - 1) SWRITE2(d + 2);      // slot (d+2)&3 disjoint
        __syncthreads();
    }
#undef SLOAD2
#undef SWRITE2
#undef COMPUTE_D
}

// ---------------------------------------------------------------------------
// Kernel 2: gemm1 via bf16 MFMA 16x16x32. Block = (b, chunk of 1024 s).
// grid = 4*64 = 256 x 256 thr (4 waves). Per 128-s subtile: stage q,k bf16
// [64][136] (pad 8), barrier, 4 K-steps; A-frag (q rows = c) and B-frag
// (k rows = k) are contiguous bf16x8 -- natural layout, no transpose.
// Wave w owns c-rows [16w,16w+16); partial attn[64][64] per block.
// ---------------------------------------------------------------------------
__global__ __launch_bounds__(256) void gemm1_mfma(
    const unsigned short* __restrict__ qb, const unsigned short* __restrict__ kb,
    float* __restrict__ part)
{
    __shared__ unsigned short lq[64*136];
    __shared__ unsigned short lk[64*136];

    int bid   = blockIdx.x;
    int b     = bid >> 6;
    int chunk = bid & 63;
    int tid   = threadIdx.x;
    int lane  = tid & 63;
    int wid   = tid >> 6;
    int c0    = wid << 4;
    int lr    = lane & 15;
    int kq    = lane >> 4;

    const unsigned short* qsrc = qb + (size_t)b*CC*SS;
    const unsigned short* ksrc = kb + (size_t)b*KK*SS;

    f32x4 acc[4];
    #pragma unroll
    for (int j = 0; j < 4; ++j) acc[j] = (f32x4){0.f, 0.f, 0.f, 0.f};

    const int sbase = chunk << 10;                     // 1024 s per block
    for (int sc = 0; sc < 8; ++sc) {
        const int s0 = sbase + (sc << 7);              // 128-s subtile
        __syncthreads();
        #pragma unroll
        for (int it = 0; it < 8; ++it) {
            const int idx  = it*256 + tid;             // 0..2047
            const int tile = idx >> 10;
            const int row  = (idx >> 4) & 63;
            const int ch8  = idx & 15;
            const unsigned short* s_ = (tile ? ksrc : qsrc) + (size_t)row*SS + s0 + ch8*8;
            unsigned short* d_ = (tile ? lk : lq) + row*136 + ch8*8;
            *(uint4*)d_ = *(const uint4*)s_;
        }
        __syncthreads();
        #pragma unroll
        for (int ss = 0; ss < 4; ++ss) {
            const int scol = ss*32 + kq*8;
            bf16x8 a = *(const bf16x8*)&lq[(c0 + lr)*136 + scol];
            #pragma unroll
            for (int j = 0; j < 4; ++j) {
                bf16x8 bv = *(const bf16x8*)&lk[(j*16 + lr)*136 + scol];
                acc[j] = __builtin_amdgcn_mfma_f32_16x16x32_bf16(a, bv, acc[j], 0, 0, 0);
            }
        }
    }

    float* pb = part + ((size_t)(b*NCH2 + chunk)) * (CC*KK);
    #pragma unroll
    for (int j = 0; j < 4; ++j)
        #pragma unroll
        for (int r = 0; r < 4; ++r)
            pb[(c0 + kq*4 + r)*KK + j*16 + lr] = acc[j][r];
}

// ---------------------------------------------------------------------------
// Kernel 3: reduce 64 chunk-partials -> attn logits (x 1/sqrt(64) = 0.125)
// ---------------------------------------------------------------------------
__global__ __launch_bounds__(256) void reduce_attn(
    const float* __restrict__ part, float* __restrict__ attn)
{
    int bid = blockIdx.x;            // b*64 + c
    int b = bid >> 6, c = bid & 63;
    int tid = threadIdx.x;
    int k = tid & 63, g = tid >> 6;
    float s = 0.f;
    for (int ch = g; ch < NCH2; ch += 4)
        s += part[(size_t)(b*NCH2 + ch)*(CC*KK) + c*KK + k];
    __shared__ float red[256];
    red[tid] = s;
    __syncthreads();
    if (tid < 64) {
        float tot = red[tid] + red[tid+64] + red[tid+128] + red[tid+192];
        attn[b*CC*KK + c*KK + tid] = tot * 0.125f;
    }
}

// ---------------------------------------------------------------------------
// Kernel 4: per-batch softmax over K (rows) + top-6 mask per column over C.
// Strict ">" == lax.top_k lowest-index-first tie break. Writes attn_m (out 1).
// ---------------------------------------------------------------------------
__global__ __launch_bounds__(64) void softmax_topk(
    const float* __restrict__ attn, float* __restrict__ attn_m)
{
    __shared__ float p[64*65];
    int b = blockIdx.x;
    int t = threadIdx.x;
    for (int i = 0; i < 64; ++i) p[i*65 + t] = attn[b*4096 + i*64 + t];
    __syncthreads();
    float m = -1e30f;
    for (int k = 0; k < 64; ++k) m = fmaxf(m, p[t*65 + k]);
    float sum = 0.f;
    for (int k = 0; k < 64; ++k) { float e = expf(p[t*65+k] - m); p[t*65+k] = e; sum += e; }
    float inv = 1.f / sum;
    for (int k = 0; k < 64; ++k) p[t*65+k] *= inv;
    __syncthreads();
    unsigned long long chosen = 0ull;
    #pragma unroll
    for (int pass = 0; pass < TOPN; ++pass) {
        float best = -1.f; int bi = 0;
        for (int c2 = 0; c2 < 64; ++c2) {
            float v = p[c2*65 + t];
            if (!((chosen >> c2) & 1ull) && v > best) { best = v; bi = c2; }
        }
        chosen |= 1ull << bi;
    }
    for (int c2 = 0; c2 < 64; ++c2) {
        float v = p[c2*65 + t];
        attn_m[b*4096 + c2*64 + t] = ((chosen >> c2) & 1ull) ? v : 0.f;
    }
}

// ---------------------------------------------------------------------------
// Kernel 5: out = x_q + attn_m @ v. Per block: one batch, 512-s chunk
// (4 subtiles of 128). attn_m held transposed [k][c] in LDS; v read as bf16
// and unpacked to f32 in LDS at stage time (compute math unchanged f32).
// ---------------------------------------------------------------------------
__global__ __launch_bounds__(256) void gemm2_out(
    const float* __restrict__ attn_m, const unsigned short* __restrict__ v,
    const float* __restrict__ xq, float* __restrict__ out)
{
    __shared__ float amt[64][68];    // [k][c]
    __shared__ float vt[64][132];    // [k][s]
    int bid = blockIdx.x;
    int b  = bid >> 7;
    int ch = bid & 127;
    int tid = threadIdx.x;
    for (int i = 0; i < 16; ++i) {
        int idx = i*256 + tid;                 // idx = c*64 + k
        amt[idx & 63][idx >> 6] = attn_m[b*4096 + idx];
    }
    int c0 = (tid >> 4) * 4;      // 0..60
    int s0 = (tid & 15) * 8;      // 0..120
    const unsigned short* vb = v + (size_t)b*KK*SS;
    const float* xb = xq + (size_t)b*CC*SS;
    float* ob = out + (size_t)b*CC*SS;
    int sb0 = ch * 512;
    for (int st = 0; st < 4; ++st) {
        int sb = sb0 + st*128;
        __syncthreads();
        #pragma unroll
        for (int i = 0; i < 4; ++i) {
            int idx = i*256 + tid;             // 0..1023
            int k   = idx >> 4;                // 0..63
            int s8  = (idx & 15) * 8;          // 0..120
            uint4 pk = *(const uint4*)&vb[(size_t)k*SS + sb + s8];
            float* dst = &vt[k][s8];
            dst[0] = bf2f((unsigned short)(pk.x & 0xffff));
            dst[1] = bf2f((unsigned short)(pk.x >> 16));
            dst[2] = bf2f((unsigned short)(pk.y & 0xffff));
            dst[3] = bf2f((unsigned short)(pk.y >> 16));
            dst[4] = bf2f((unsigned short)(pk.z & 0xffff));
            dst[5] = bf2f((unsigned short)(pk.z >> 16));
            dst[6] = bf2f((unsigned short)(pk.w & 0xffff));
            dst[7] = bf2f((unsigned short)(pk.w >> 16));
        }
        __syncthreads();
        float acc[4][8] = {};
        #pragma unroll 8
        for (int k = 0; k < 64; ++k) {
            float4 a  = *(const float4*)&amt[k][c0];
            float4 v0 = *(const float4*)&vt[k][s0];
            float4 v1 = *(const float4*)&vt[k][s0+4];
            float av[4] = {a.x,a.y,a.z,a.w};
            float vv[8] = {v0.x,v0.y,v0.z,v0.w,v1.x,v1.y,v1.z,v1.w};
            #pragma unroll
            for (int i = 0; i < 4; ++i)
                #pragma unroll
                for (int j = 0; j < 8; ++j)
                    acc[i][j] = fmaf(av[i], vv[j], acc[i][j]);
        }
        #pragma unroll
        for (int i = 0; i < 4; ++i) {
            int off = (c0+i)*SS + sb + s0;
            float4 x0 = *(const float4*)&xb[off];
            float4 x1 = *(const float4*)&xb[off+4];
            *(float4*)&ob[off]   = make_float4(acc[i][0]+x0.x, acc[i][1]+x0.y,
                                               acc[i][2]+x0.z, acc[i][3]+x0.w);
            *(float4*)&ob[off+4] = make_float4(acc[i][4]+x1.x, acc[i][5]+x1.y,
                                               acc[i][6]+x1.z, acc[i][7]+x1.w);
        }
    }
}

// ---------------------------------------------------------------------------
extern "C" void kernel_launch(void* const* d_in, const int* in_sizes, int n_in,
                              void* d_out, int out_size, void* d_ws, size_t ws_size,
                              hipStream_t stream)
{
    const float* xq  = (const float*)d_in[0];
    const float* xkv = (const float*)d_in[1];
    const float* wq  = (const float*)d_in[2];
    const float* bq  = (const float*)d_in[3];
    const float* wk  = (const float*)d_in[4];
    const float* bk  = (const float*)d_in[5];
    const float* wv  = (const float*)d_in[6];
    const float* bv  = (const float*)d_in[7];
    float* out = (float*)d_out;

    // workspace: k (bf16 32MB), v (bf16 32MB), part (4MB), attn (64KB)
    unsigned short* k_ws = (unsigned short*)d_ws;
    unsigned short* v_ws = k_ws + (size_t)BB*KK*SS;
    float* part = (float*)(v_ws + (size_t)BB*KK*SS);
    float* attn = part + (size_t)BB*NCH2*CC*KK;

    unsigned short* q_bf = (unsigned short*)out;  // 32MB in out region,
                                                  // overwritten by gemm2_out
    float* attn_m = out + (size_t)BB*CC*SS;       // output 1 (B*C*K floats)

    conv_uni   <<<BB*CC*4,   128, 0, stream>>>(xq, xkv, wq, bq, wk, bk, wv, bv,
                                               q_bf, k_ws, v_ws);
    gemm1_mfma <<<BB*NCH2,   256, 0, stream>>>(q_bf, k_ws, part);
    reduce_attn<<<BB*CC,     256, 0, stream>>>(part, attn);
    softmax_topk<<<BB,        64, 0, stream>>>(attn, attn_m);
    gemm2_out  <<<BB*128,    256, 0, stream>>>(attn_m, v_ws, xq, out);
}